// Round 9
// baseline (407.944 us; speedup 1.0000x reference)
//
#include <hip/hip_runtime.h>

typedef __attribute__((ext_vector_type(4))) float f32x4;
typedef __attribute__((ext_vector_type(8))) short bf16x8;

__device__ __forceinline__ short f2bf(float f) {
    union { float f; unsigned u; } v; v.f = f;
    unsigned u = v.u + 0x7FFFu + ((v.u >> 16) & 1u);   // RNE
    return (short)(u >> 16);
}
__device__ __forceinline__ int pack_bf2(float a, float b) {
    union { float f; unsigned u; } ua, ub; ua.f = a; ub.f = b;
    unsigned x = ua.u + 0x8000u, y = ub.u + 0x8000u;   // round half-up
    return (int)__builtin_amdgcn_perm(y, x, 0x07060302u);
}

// sum over lanes {l, l^16, l^32, l^48}.
// gfx950 permlane{16,32}_swap: VALU pipe, no DS traffic. Verified on-HW (r3).
#if __has_builtin(__builtin_amdgcn_permlane16_swap) && \
    __has_builtin(__builtin_amdgcn_permlane32_swap)
__device__ __forceinline__ float quad_sum(float dp) {
    unsigned u = __float_as_uint(dp);
    auto r1 = __builtin_amdgcn_permlane16_swap(u, u, false, false);
    float s = __uint_as_float(r1[0]) + __uint_as_float(r1[1]);
    unsigned v = __float_as_uint(s);
    auto r2 = __builtin_amdgcn_permlane32_swap(v, v, false, false);
    return __uint_as_float(r2[0]) + __uint_as_float(r2[1]);
}
#else
__device__ __forceinline__ float quad_sum(float dp) {
    dp += __shfl_xor(dp, 16, 64);
    dp += __shfl_xor(dp, 32, 64);
    return dp;
}
#endif

// ---------------------------------------------------------------------------
// Prep (16 blocks x 64 = ONE WAVE per component):
// Full-register right-looking Cholesky: lane j owns row j of A in row[64]
// (fully unrolled -> static indices -> registers). Per step k:
//   diag from shfl(row[k],k); lanes scale row[k]; rank-1 update via
//   shfl(row[k],i) + fma. Zero LDS / zero barriers in the factorization.
// Upper-triangle lanes (i>j) accumulate garbage that is never sourced:
// every shfl reads lane i>k (strict lower triangle + diag).
// Then: dump L to LDS (stride 65, conflict-free), bias via shfl, and the
// same fragment pack as before (frags 4,6 all-zero; main skips them).
// Replaces the 21 us blocked version (16 barriers, wave-0-only panel).
// ---------------------------------------------------------------------------
__global__ __launch_bounds__(64) void gmm_prep(
        const float* __restrict__ Ainv,
        const float* __restrict__ means,
        short* __restrict__ AbP16,
        float* __restrict__ biasP) {
    __shared__ float sL[64 * 65];
    __shared__ float sm[64];
    const int c = blockIdx.x, l = threadIdx.x;   // lane 0..63
    const float* A = Ainv + c * 4096;

    // lane l loads row l (L2-resident after first block touches it)
    float row[64];
    #pragma unroll
    for (int i = 0; i < 16; ++i) {
        f32x4 v = *(const f32x4*)(A + l * 64 + i * 4);
        row[i * 4 + 0] = v[0]; row[i * 4 + 1] = v[1];
        row[i * 4 + 2] = v[2]; row[i * 4 + 3] = v[3];
    }
    sm[l] = means[c * 64 + l];

    // in-register Cholesky (fully unrolled: ~2016 shfl+fma, static indices)
    #pragma unroll
    for (int k = 0; k < 64; ++k) {
        float diag = __shfl(row[k], k, 64);
        float s = __builtin_sqrtf(diag);
        float inv = 1.f / s;
        row[k] = (l == k) ? s : row[k] * inv;
        #pragma unroll
        for (int i = k + 1; i < 64; ++i) {
            float lik = __shfl(row[k], i, 64);   // lane i's scaled L[i][k]
            row[i] = fmaf(-row[k], lik, row[i]);
        }
    }

    // dump L rows to LDS; stride 65 -> column walks conflict-free
    #pragma unroll
    for (int i = 0; i < 64; ++i) sL[l * 65 + i] = row[i];
    __syncthreads();

    // b[j] = (L^T m)[j] = sum_{k>=j} L[k][j] m[k]; lane j computes b[j]
    float p = 0.f;
    #pragma unroll 1
    for (int k = 0; k < 64; ++k) {
        float Lv = sL[k * 65 + l];
        float mv = sm[k];
        p = (k >= l) ? fmaf(Lv, mv, p) : p;
    }
    {   // biasP[c][t] = -b[pi(t)] via shfl (no LDS round-trip)
        int rt = l >> 4, qh = (l >> 2) & 3, r = l & 3;
        int pjb = (rt >> 1) * 32 + 8 * qh + 4 * (rt & 1) + r;
        biasP[c * 64 + l] = -__shfl(p, pjb, 64);
    }

    // permuted M = L^T fragments (8 reps x 64 lanes = 512 frags)
    #pragma unroll
    for (int rep = 0; rep < 8; ++rep) {
        int f = rep * 64 + l;
        int rt = f >> 7, kc = (f >> 6) & 1, L_ = f & 63;
        int ln = L_ & 15, q = L_ >> 4;
        int pj = (rt >> 1) * 32 + 8 * (ln >> 2) + 4 * (rt & 1) + (ln & 3);
        int kbase = 32 * kc + 8 * q;
        bf16x8 v;
        #pragma unroll
        for (int j = 0; j < 8; ++j) {
            int kk = kbase + j;
            float x = (kk >= pj) ? sL[kk * 65 + pj] : 0.f;   // M[pj][kk]=L[kk][pj]
            v[j] = f2bf(x);
        }
        *(bf16x8*)(AbP16 + c * 4096 + f * 8) = v;
    }
}

union BFrag { bf16x8 v; int i[4]; };

// ---------------------------------------------------------------------------
// Main (1024 blocks x 256) — round-7 structure; the ONLY change is
// #pragma unroll 2 on the comp loop: both iterations' 10 loads (6 af +
// 4 bias) hoist to the top of the straight-line unrolled body, so comp
// c+1's L2 latency hides under comp c's MFMA+VALU. No loop-carried
// register state, no conditional aggregate assignment (the r2/r8 spill
// trap). 4 waves x 64 samples; NO LDS, NO barriers; M upper-triangular:
// 6 MFMA + 6 af loads per comp; d = sum z^2; permlane quad reduction;
// coalesced store.
// ---------------------------------------------------------------------------
__global__ __launch_bounds__(256, 4) void gmm_main(
    const float* __restrict__ X,
    const float* __restrict__ weights,
    const short* __restrict__ AbP16,
    const float* __restrict__ biasP,
    float* __restrict__ out) {

    const int tid = threadIdx.x;
    const int lane = tid & 63, w = tid >> 6;
    const int q = lane >> 4, ln = lane & 15;
    const int base = blockIdx.x * 256 + w * 64;

    BFrag xb[4][2];
    #pragma unroll
    for (int t = 0; t < 4; ++t) {
        const float* xr = X + (size_t)(base + t * 16 + ln) * 64 + 8 * q;
        #pragma unroll
        for (int kc = 0; kc < 2; ++kc) {
            f32x4 a = *(const f32x4*)(xr + 32 * kc);
            f32x4 b = *(const f32x4*)(xr + 32 * kc + 4);
            xb[t][kc].i[0] = pack_bf2(a[0], a[1]);
            xb[t][kc].i[1] = pack_bf2(a[2], a[3]);
            xb[t][kc].i[2] = pack_bf2(b[0], b[1]);
            xb[t][kc].i[3] = pack_bf2(b[2], b[3]);
        }
    }

    float slog[4] = {0.f, 0.f, 0.f, 0.f};

    #pragma unroll 2
    for (int c = 0; c < 16; ++c) {
        const short* aP = AbP16 + c * 4096 + lane * 8;
        bf16x8 af0 = *(const bf16x8*)(aP + 0 * 512);   // rt0 kc0
        bf16x8 af1 = *(const bf16x8*)(aP + 1 * 512);   // rt0 kc1
        bf16x8 af2 = *(const bf16x8*)(aP + 2 * 512);   // rt1 kc0
        bf16x8 af3 = *(const bf16x8*)(aP + 3 * 512);   // rt1 kc1
        bf16x8 af5 = *(const bf16x8*)(aP + 5 * 512);   // rt2 kc1 (kc0 zero)
        bf16x8 af7 = *(const bf16x8*)(aP + 7 * 512);   // rt3 kc1 (kc0 zero)
        f32x4 bias[4];
        #pragma unroll
        for (int rt = 0; rt < 4; ++rt)
            bias[rt] = *(const f32x4*)(biasP + c * 64 + rt * 16 + q * 4);
        const float wcc = weights[c];

        #pragma unroll
        for (int t = 0; t < 4; ++t) {
            f32x4 a0 = __builtin_amdgcn_mfma_f32_16x16x32_bf16(af0, xb[t][0].v, bias[0], 0, 0, 0);
            a0 = __builtin_amdgcn_mfma_f32_16x16x32_bf16(af1, xb[t][1].v, a0, 0, 0, 0);
            f32x4 a1 = __builtin_amdgcn_mfma_f32_16x16x32_bf16(af2, xb[t][0].v, bias[1], 0, 0, 0);
            a1 = __builtin_amdgcn_mfma_f32_16x16x32_bf16(af3, xb[t][1].v, a1, 0, 0, 0);
            f32x4 a2 = __builtin_amdgcn_mfma_f32_16x16x32_bf16(af5, xb[t][1].v, bias[2], 0, 0, 0);
            f32x4 a3 = __builtin_amdgcn_mfma_f32_16x16x32_bf16(af7, xb[t][1].v, bias[3], 0, 0, 0);

            float dp0 = a0[0] * a0[0], dp1 = a1[0] * a1[0];
            float dp2 = a2[0] * a2[0], dp3 = a3[0] * a3[0];
            #pragma unroll
            for (int i = 1; i < 4; ++i) {
                dp0 = fmaf(a0[i], a0[i], dp0);
                dp1 = fmaf(a1[i], a1[i], dp1);
                dp2 = fmaf(a2[i], a2[i], dp2);
                dp3 = fmaf(a3[i], a3[i], dp3);
            }
            float dp = quad_sum((dp0 + dp1) + (dp2 + dp3));
            float d = fmaxf(dp, 1e-30f);
            slog[t] = fmaf(wcc, __builtin_amdgcn_logf(d), slog[t]);
        }
    }

    // slog[] identical across each quad after quad_sum: lane (q,ln)
    // writes sample q*16+ln -> one coalesced 64-wide store per wave
    float s0 = (q & 1) ? slog[1] : slog[0];
    float s1 = (q & 1) ? slog[3] : slog[2];
    float sv = (q & 2) ? s1 : s0;
    out[base + lane] = __builtin_amdgcn_exp2f(sv);
}

extern "C" void kernel_launch(void* const* d_in, const int* in_sizes, int n_in,
                              void* d_out, int out_size, void* d_ws, size_t ws_size,
                              hipStream_t stream) {
    const float* X       = (const float*)d_in[0];
    const float* Ainv    = (const float*)d_in[1];
    const float* means   = (const float*)d_in[2];
    const float* weights = (const float*)d_in[3];
    float* out = (float*)d_out;
    const int N = in_sizes[0] / 64;

    short* AbP16 = (short*)d_ws;                       // 131072 B
    float* biasP = (float*)((char*)d_ws + 131072);     // 4096 B

    gmm_prep<<<dim3(16), dim3(64), 0, stream>>>(Ainv, means, AbP16, biasP);
    gmm_main<<<dim3(N / 256), dim3(256), 0, stream>>>(X, weights, AbP16, biasP, out);
}

// Round 10
// 149.207 us; speedup vs baseline: 2.7341x; 2.7341x over previous
//
#include <hip/hip_runtime.h>

typedef __attribute__((ext_vector_type(4))) float f32x4;
typedef __attribute__((ext_vector_type(8))) short bf16x8;

__device__ __forceinline__ short f2bf(float f) {
    union { float f; unsigned u; } v; v.f = f;
    unsigned u = v.u + 0x7FFFu + ((v.u >> 16) & 1u);   // RNE
    return (short)(u >> 16);
}
__device__ __forceinline__ int pack_bf2(float a, float b) {
    union { float f; unsigned u; } ua, ub; ua.f = a; ub.f = b;
    unsigned x = ua.u + 0x8000u, y = ub.u + 0x8000u;   // round half-up
    return (int)__builtin_amdgcn_perm(y, x, 0x07060302u);
}

// sum over lanes {l, l^16, l^32, l^48}.
// gfx950 permlane{16,32}_swap: VALU pipe, no DS traffic. Verified on-HW (r3).
#if __has_builtin(__builtin_amdgcn_permlane16_swap) && \
    __has_builtin(__builtin_amdgcn_permlane32_swap)
__device__ __forceinline__ float quad_sum(float dp) {
    unsigned u = __float_as_uint(dp);
    auto r1 = __builtin_amdgcn_permlane16_swap(u, u, false, false);
    float s = __uint_as_float(r1[0]) + __uint_as_float(r1[1]);
    unsigned v = __float_as_uint(s);
    auto r2 = __builtin_amdgcn_permlane32_swap(v, v, false, false);
    return __uint_as_float(r2[0]) + __uint_as_float(r2[1]);
}
#else
__device__ __forceinline__ float quad_sum(float dp) {
    dp += __shfl_xor(dp, 16, 64);
    dp += __shfl_xor(dp, 32, 64);
    return dp;
}
#endif

// ---------------------------------------------------------------------------
// Prep (16 blocks x 256): BLOCKED Cholesky A = L·L^T (B=8) — byte-identical
// revert to the round-7 version (proven ~21 us; the r9 "register" variant
// hit 256 VGPR + scratch + a serial 2016-shfl chain = 292 us).
// ---------------------------------------------------------------------------
__global__ void gmm_prep(const float* __restrict__ Ainv,
                         const float* __restrict__ means,
                         short* __restrict__ AbP16,
                         float* __restrict__ biasP) {
    __shared__ float sA[64 * 65];
    __shared__ float sm[64];
    __shared__ float sb[64];
    const int c = blockIdx.x, t = threadIdx.x;
    const float* A = Ainv + c * 4096;
    #pragma unroll
    for (int i = 0; i < 16; ++i) {         // scalar coalesced stage (stride 65)
        int ft = i * 256 + t;
        sA[(ft >> 6) * 65 + (ft & 63)] = A[ft];
    }
    if (t < 64) sm[t] = means[c * 64 + t];
    __syncthreads();

    #pragma unroll 1
    for (int kb = 0; kb < 8; ++kb) {
        const int k0 = kb * 8;
        if (t < 64) {                      // ---- panel: wave 0, registers ----
            const int j = k0 + t;
            const bool act = (j < 64);
            const int jj = act ? j : 63;
            float pc[8];
            #pragma unroll
            for (int i = 0; i < 8; ++i) pc[i] = sA[jj * 65 + k0 + i];
            #pragma unroll
            for (int kk = 0; kk < 8; ++kk) {
                float diag = __shfl(pc[kk], kk, 64);
                float s = __builtin_sqrtf(diag);
                float inv = 1.f / s;
                if (t == kk)     pc[kk] = s;
                else if (t > kk) pc[kk] *= inv;
                #pragma unroll
                for (int i = kk + 1; i < 8; ++i) {
                    float lik = __shfl(pc[kk], i, 64);
                    if (t > kk) pc[i] = fmaf(-pc[kk], lik, pc[i]);
                }
            }
            if (act) {
                #pragma unroll
                for (int i = 0; i < 8; ++i) sA[j * 65 + k0 + i] = pc[i];
            }
        }
        __syncthreads();
        {   // ---- trailing rank-8 update ----
            const int r0 = k0 + 8;
            const int W = 64 - r0;
            if (W > 0) {
                const int qc = t & 15;
                const int jr = t >> 4;
                if (qc * 4 < W) {
                    const int i0 = r0 + qc * 4;
                    for (int j = r0 + jr; j < 64; j += 16) {
                        float a0 = 0.f, a1 = 0.f, a2 = 0.f, a3 = 0.f;
                        #pragma unroll
                        for (int k = 0; k < 8; ++k) {
                            float ljk = sA[j * 65 + k0 + k];
                            a0 = fmaf(ljk, sA[(i0 + 0) * 65 + k0 + k], a0);
                            a1 = fmaf(ljk, sA[(i0 + 1) * 65 + k0 + k], a1);
                            a2 = fmaf(ljk, sA[(i0 + 2) * 65 + k0 + k], a2);
                            a3 = fmaf(ljk, sA[(i0 + 3) * 65 + k0 + k], a3);
                        }
                        sA[j * 65 + i0 + 0] -= a0;
                        sA[j * 65 + i0 + 1] -= a1;
                        sA[j * 65 + i0 + 2] -= a2;
                        sA[j * 65 + i0 + 3] -= a3;
                    }
                }
            }
        }
        __syncthreads();
    }

    {   // b[j] = (L^T m)[j] = sum_{k>=j} L[k][j] m[k]
        int j = t >> 2, seg = t & 3;
        float p = 0.f;
        #pragma unroll
        for (int k2 = 0; k2 < 16; ++k2) {
            int k = seg * 16 + k2;
            float Mv = (k >= j) ? sA[k * 65 + j] : 0.f;
            p += Mv * sm[k];
        }
        p += __shfl_xor(p, 1, 64); p += __shfl_xor(p, 2, 64);
        if (seg == 0) sb[j] = p;
    }
    __syncthreads();
    if (t < 64) {
        int rt = t >> 4, qh = (t >> 2) & 3, r = t & 3;
        int pj = (rt >> 1) * 32 + 8 * qh + 4 * (rt & 1) + r;
        biasP[c * 64 + t] = -sb[pj];
    }
    #pragma unroll
    for (int rep = 0; rep < 2; ++rep) {     // permuted M = L^T fragments
        int f = rep * 256 + t;
        int rt = f >> 7, kc = (f >> 6) & 1, L = f & 63;
        int ln = L & 15, q = L >> 4;
        int pj = (rt >> 1) * 32 + 8 * (ln >> 2) + 4 * (rt & 1) + (ln & 3);
        int kbase = 32 * kc + 8 * q;
        bf16x8 v;
        #pragma unroll
        for (int j = 0; j < 8; ++j) {
            int kk = kbase + j;
            float x = (kk >= pj) ? sA[kk * 65 + pj] : 0.f;
            v[j] = f2bf(x);
        }
        *(bf16x8*)(AbP16 + c * 4096 + f * 8) = v;
    }
}

union BFrag { bf16x8 v; int i[4]; };

// ---------------------------------------------------------------------------
// Main (2048 blocks x 256): 4 waves x 32 SAMPLES each -> 8 waves/SIMD
// (double the TLP of every prior round; occupancy steps at VGPR 64).
// To fit 64 VGPR: xb = 16 regs (2 tiles), and each comp is split into two
// sequential phases so only one load-set is live at a time:
//   phase A: af0..af3 + b0,b1 -> rows 0..31, dpA[t] = dp0+dp1
//   phase B: af5,af7  + b2,b3 -> rows 32..63, dp = dpA[t]+(dp2+dp3)
// (bit-identical add order to round 7). NO LDS, NO barriers; af/bias are
// L1-served (same addresses for every wave). Coalesced half-wave store.
// ---------------------------------------------------------------------------
__global__ __launch_bounds__(256, 8) void gmm_main(
    const float* __restrict__ X,
    const float* __restrict__ weights,
    const short* __restrict__ AbP16,
    const float* __restrict__ biasP,
    float* __restrict__ out) {

    const int tid = threadIdx.x;
    const int lane = tid & 63, w = tid >> 6;
    const int q = lane >> 4, ln = lane & 15;
    const int base = blockIdx.x * 128 + w * 32;

    // x -> persistent packed bf16 B-frags (2 tiles x 2 kc = 16 VGPRs)
    BFrag xb[2][2];
    #pragma unroll
    for (int t = 0; t < 2; ++t) {
        const float* xr = X + (size_t)(base + t * 16 + ln) * 64 + 8 * q;
        #pragma unroll
        for (int kc = 0; kc < 2; ++kc) {
            f32x4 a = *(const f32x4*)(xr + 32 * kc);
            f32x4 b = *(const f32x4*)(xr + 32 * kc + 4);
            xb[t][kc].i[0] = pack_bf2(a[0], a[1]);
            xb[t][kc].i[1] = pack_bf2(a[2], a[3]);
            xb[t][kc].i[2] = pack_bf2(b[0], b[1]);
            xb[t][kc].i[3] = pack_bf2(b[2], b[3]);
        }
    }

    float slog[2] = {0.f, 0.f};

    #pragma unroll 1
    for (int c = 0; c < 16; ++c) {
        const short* aP = AbP16 + c * 4096 + lane * 8;
        const float* bP = biasP + c * 64 + q * 4;
        const float wcc = weights[c];

        // ---- phase A: rows 0..31 ----
        bf16x8 af0 = *(const bf16x8*)(aP + 0 * 512);
        bf16x8 af1 = *(const bf16x8*)(aP + 1 * 512);
        bf16x8 af2 = *(const bf16x8*)(aP + 2 * 512);
        bf16x8 af3 = *(const bf16x8*)(aP + 3 * 512);
        f32x4 b0 = *(const f32x4*)(bP);
        f32x4 b1 = *(const f32x4*)(bP + 16);
        float dpA[2];
        #pragma unroll
        for (int t = 0; t < 2; ++t) {
            f32x4 a0 = __builtin_amdgcn_mfma_f32_16x16x32_bf16(af0, xb[t][0].v, b0, 0, 0, 0);
            a0 = __builtin_amdgcn_mfma_f32_16x16x32_bf16(af1, xb[t][1].v, a0, 0, 0, 0);
            f32x4 a1 = __builtin_amdgcn_mfma_f32_16x16x32_bf16(af2, xb[t][0].v, b1, 0, 0, 0);
            a1 = __builtin_amdgcn_mfma_f32_16x16x32_bf16(af3, xb[t][1].v, a1, 0, 0, 0);
            float dp0 = a0[0] * a0[0], dp1 = a1[0] * a1[0];
            #pragma unroll
            for (int i = 1; i < 4; ++i) {
                dp0 = fmaf(a0[i], a0[i], dp0);
                dp1 = fmaf(a1[i], a1[i], dp1);
            }
            dpA[t] = dp0 + dp1;
        }

        // ---- phase B: rows 32..63 (kc0 frags are zero -> skipped) ----
        bf16x8 af5 = *(const bf16x8*)(aP + 5 * 512);
        bf16x8 af7 = *(const bf16x8*)(aP + 7 * 512);
        f32x4 b2 = *(const f32x4*)(bP + 32);
        f32x4 b3 = *(const f32x4*)(bP + 48);
        #pragma unroll
        for (int t = 0; t < 2; ++t) {
            f32x4 a2 = __builtin_amdgcn_mfma_f32_16x16x32_bf16(af5, xb[t][1].v, b2, 0, 0, 0);
            f32x4 a3 = __builtin_amdgcn_mfma_f32_16x16x32_bf16(af7, xb[t][1].v, b3, 0, 0, 0);
            float dp2 = a2[0] * a2[0], dp3 = a3[0] * a3[0];
            #pragma unroll
            for (int i = 1; i < 4; ++i) {
                dp2 = fmaf(a2[i], a2[i], dp2);
                dp3 = fmaf(a3[i], a3[i], dp3);
            }
            float dp = quad_sum(dpA[t] + (dp2 + dp3));
            float d = fmaxf(dp, 1e-30f);
            slog[t] = fmaf(wcc, __builtin_amdgcn_logf(d), slog[t]);
        }
    }

    // slog[t] uniform across each quad after quad_sum: lanes q=0,1 store
    // tiles 0,1 -> one coalesced 32-wide (128 B) store per wave
    float sv = (q & 1) ? slog[1] : slog[0];
    if (q < 2) out[base + q * 16 + ln] = __builtin_amdgcn_exp2f(sv);
}

extern "C" void kernel_launch(void* const* d_in, const int* in_sizes, int n_in,
                              void* d_out, int out_size, void* d_ws, size_t ws_size,
                              hipStream_t stream) {
    const float* X       = (const float*)d_in[0];
    const float* Ainv    = (const float*)d_in[1];
    const float* means   = (const float*)d_in[2];
    const float* weights = (const float*)d_in[3];
    float* out = (float*)d_out;
    const int N = in_sizes[0] / 64;

    short* AbP16 = (short*)d_ws;                       // 131072 B
    float* biasP = (float*)((char*)d_ws + 131072);     // 4096 B

    gmm_prep<<<dim3(16), dim3(256), 0, stream>>>(Ainv, means, AbP16, biasP);
    gmm_main<<<dim3(N / 128), dim3(256), 0, stream>>>(X, weights, AbP16, biasP, out);
}

// Round 11
// 138.577 us; speedup vs baseline: 2.9438x; 1.0767x over previous
//
#include <hip/hip_runtime.h>

typedef __attribute__((ext_vector_type(4))) float f32x4;
typedef __attribute__((ext_vector_type(8))) short bf16x8;

__device__ __forceinline__ short f2bf(float f) {
    union { float f; unsigned u; } v; v.f = f;
    unsigned u = v.u + 0x7FFFu + ((v.u >> 16) & 1u);   // RNE
    return (short)(u >> 16);
}
__device__ __forceinline__ int pack_bf2(float a, float b) {
    union { float f; unsigned u; } ua, ub; ua.f = a; ub.f = b;
    unsigned x = ua.u + 0x8000u, y = ub.u + 0x8000u;   // round half-up
    return (int)__builtin_amdgcn_perm(y, x, 0x07060302u);
}

// ---------------------------------------------------------------------------
// Prep (16 blocks x 256): BLOCKED Cholesky A = L·L^T (B=8) — byte-identical
// to the proven round-7 version (~21 us).
// ---------------------------------------------------------------------------
__global__ void gmm_prep(const float* __restrict__ Ainv,
                         const float* __restrict__ means,
                         short* __restrict__ AbP16,
                         float* __restrict__ biasP) {
    __shared__ float sA[64 * 65];
    __shared__ float sm[64];
    __shared__ float sb[64];
    const int c = blockIdx.x, t = threadIdx.x;
    const float* A = Ainv + c * 4096;
    #pragma unroll
    for (int i = 0; i < 16; ++i) {         // scalar coalesced stage (stride 65)
        int ft = i * 256 + t;
        sA[(ft >> 6) * 65 + (ft & 63)] = A[ft];
    }
    if (t < 64) sm[t] = means[c * 64 + t];
    __syncthreads();

    #pragma unroll 1
    for (int kb = 0; kb < 8; ++kb) {
        const int k0 = kb * 8;
        if (t < 64) {                      // ---- panel: wave 0, registers ----
            const int j = k0 + t;
            const bool act = (j < 64);
            const int jj = act ? j : 63;
            float pc[8];
            #pragma unroll
            for (int i = 0; i < 8; ++i) pc[i] = sA[jj * 65 + k0 + i];
            #pragma unroll
            for (int kk = 0; kk < 8; ++kk) {
                float diag = __shfl(pc[kk], kk, 64);
                float s = __builtin_sqrtf(diag);
                float inv = 1.f / s;
                if (t == kk)     pc[kk] = s;
                else if (t > kk) pc[kk] *= inv;
                #pragma unroll
                for (int i = kk + 1; i < 8; ++i) {
                    float lik = __shfl(pc[kk], i, 64);
                    if (t > kk) pc[i] = fmaf(-pc[kk], lik, pc[i]);
                }
            }
            if (act) {
                #pragma unroll
                for (int i = 0; i < 8; ++i) sA[j * 65 + k0 + i] = pc[i];
            }
        }
        __syncthreads();
        {   // ---- trailing rank-8 update ----
            const int r0 = k0 + 8;
            const int W = 64 - r0;
            if (W > 0) {
                const int qc = t & 15;
                const int jr = t >> 4;
                if (qc * 4 < W) {
                    const int i0 = r0 + qc * 4;
                    for (int j = r0 + jr; j < 64; j += 16) {
                        float a0 = 0.f, a1 = 0.f, a2 = 0.f, a3 = 0.f;
                        #pragma unroll
                        for (int k = 0; k < 8; ++k) {
                            float ljk = sA[j * 65 + k0 + k];
                            a0 = fmaf(ljk, sA[(i0 + 0) * 65 + k0 + k], a0);
                            a1 = fmaf(ljk, sA[(i0 + 1) * 65 + k0 + k], a1);
                            a2 = fmaf(ljk, sA[(i0 + 2) * 65 + k0 + k], a2);
                            a3 = fmaf(ljk, sA[(i0 + 3) * 65 + k0 + k], a3);
                        }
                        sA[j * 65 + i0 + 0] -= a0;
                        sA[j * 65 + i0 + 1] -= a1;
                        sA[j * 65 + i0 + 2] -= a2;
                        sA[j * 65 + i0 + 3] -= a3;
                    }
                }
            }
        }
        __syncthreads();
    }

    {   // b[j] = (L^T m)[j] = sum_{k>=j} L[k][j] m[k]
        int j = t >> 2, seg = t & 3;
        float p = 0.f;
        #pragma unroll
        for (int k2 = 0; k2 < 16; ++k2) {
            int k = seg * 16 + k2;
            float Mv = (k >= j) ? sA[k * 65 + j] : 0.f;
            p += Mv * sm[k];
        }
        p += __shfl_xor(p, 1, 64); p += __shfl_xor(p, 2, 64);
        if (seg == 0) sb[j] = p;
    }
    __syncthreads();
    if (t < 64) {
        int rt = t >> 4, qh = (t >> 2) & 3, r = t & 3;
        int pj = (rt >> 1) * 32 + 8 * qh + 4 * (rt & 1) + r;
        biasP[c * 64 + t] = -sb[pj];
    }
    #pragma unroll
    for (int rep = 0; rep < 2; ++rep) {     // permuted M = L^T fragments
        int f = rep * 256 + t;
        int rt = f >> 7, kc = (f >> 6) & 1, L = f & 63;
        int ln = L & 15, q = L >> 4;
        int pj = (rt >> 1) * 32 + 8 * (ln >> 2) + 4 * (rt & 1) + (ln & 3);
        int kbase = 32 * kc + 8 * q;
        bf16x8 v;
        #pragma unroll
        for (int j = 0; j < 8; ++j) {
            int kk = kbase + j;
            float x = (kk >= pj) ? sA[kk * 65 + pj] : 0.f;
            v[j] = f2bf(x);
        }
        *(bf16x8*)(AbP16 + c * 4096 + f * 8) = v;
    }
}

union BFrag { bf16x8 v; int i[4]; };

// ---------------------------------------------------------------------------
// Main (1024 blocks x 256): r7 shape (4 waves x 64 samples — restores the
// per-wave VMEM amortization r10 destroyed). Two changes vs r7:
//  1) bias in LDS (4 KB staged once): per comp 6 VMEM (af) + 4 ds_read_b128
//     instead of 10 VMEM — 40% less TA traffic, DS pipe was idle.
//  2) transpose-reduce epilogue: 2-stage shfl_xor butterfly lands tile-q's
//     quad-sum in quad-lane q -> ONE log/fmax/fma per comp instead of 4.
//     Bit-identical add tree (fp add commutes); store maps lane (q,ln) ->
//     sample q*16+ln directly.
// ---------------------------------------------------------------------------
__global__ __launch_bounds__(256, 4) void gmm_main(
    const float* __restrict__ X,
    const float* __restrict__ weights,
    const short* __restrict__ AbP16,
    const float* __restrict__ biasP,
    float* __restrict__ out) {

    __shared__ float sBias[1024];          // 4 KB: [c][p] permuted rows

    const int tid = threadIdx.x;
    const int lane = tid & 63, w = tid >> 6;
    const int q = lane >> 4, ln = lane & 15;
    const int q0 = q & 1, q1 = q >> 1;
    const int base = blockIdx.x * 256 + w * 64;

    ((f32x4*)sBias)[tid] = ((const f32x4*)biasP)[tid];

    BFrag xb[4][2];
    #pragma unroll
    for (int t = 0; t < 4; ++t) {
        const float* xr = X + (size_t)(base + t * 16 + ln) * 64 + 8 * q;
        #pragma unroll
        for (int kc = 0; kc < 2; ++kc) {
            f32x4 a = *(const f32x4*)(xr + 32 * kc);
            f32x4 b = *(const f32x4*)(xr + 32 * kc + 4);
            xb[t][kc].i[0] = pack_bf2(a[0], a[1]);
            xb[t][kc].i[1] = pack_bf2(a[2], a[3]);
            xb[t][kc].i[2] = pack_bf2(b[0], b[1]);
            xb[t][kc].i[3] = pack_bf2(b[2], b[3]);
        }
    }
    __syncthreads();                       // bias staged

    float slog = 0.f;

    #pragma unroll 1
    for (int c = 0; c < 16; ++c) {
        const short* aP = AbP16 + c * 4096 + lane * 8;
        bf16x8 af0 = *(const bf16x8*)(aP + 0 * 512);   // rt0 kc0
        bf16x8 af1 = *(const bf16x8*)(aP + 1 * 512);   // rt0 kc1
        bf16x8 af2 = *(const bf16x8*)(aP + 2 * 512);   // rt1 kc0
        bf16x8 af3 = *(const bf16x8*)(aP + 3 * 512);   // rt1 kc1
        bf16x8 af5 = *(const bf16x8*)(aP + 5 * 512);   // rt2 kc1 (kc0 zero)
        bf16x8 af7 = *(const bf16x8*)(aP + 7 * 512);   // rt3 kc1 (kc0 zero)
        const float* bP = &sBias[c * 64 + q * 4];
        f32x4 b0 = *(const f32x4*)(bP);
        f32x4 b1 = *(const f32x4*)(bP + 16);
        f32x4 b2 = *(const f32x4*)(bP + 32);
        f32x4 b3 = *(const f32x4*)(bP + 48);
        const float wcc = weights[c];

        float dp[4];
        #pragma unroll
        for (int t = 0; t < 4; ++t) {
            f32x4 a0 = __builtin_amdgcn_mfma_f32_16x16x32_bf16(af0, xb[t][0].v, b0, 0, 0, 0);
            a0 = __builtin_amdgcn_mfma_f32_16x16x32_bf16(af1, xb[t][1].v, a0, 0, 0, 0);
            f32x4 a1 = __builtin_amdgcn_mfma_f32_16x16x32_bf16(af2, xb[t][0].v, b1, 0, 0, 0);
            a1 = __builtin_amdgcn_mfma_f32_16x16x32_bf16(af3, xb[t][1].v, a1, 0, 0, 0);
            f32x4 a2 = __builtin_amdgcn_mfma_f32_16x16x32_bf16(af5, xb[t][1].v, b2, 0, 0, 0);
            f32x4 a3 = __builtin_amdgcn_mfma_f32_16x16x32_bf16(af7, xb[t][1].v, b3, 0, 0, 0);

            float dp0 = a0[0] * a0[0], dp1 = a1[0] * a1[0];
            float dp2 = a2[0] * a2[0], dp3 = a3[0] * a3[0];
            #pragma unroll
            for (int i = 1; i < 4; ++i) {
                dp0 = fmaf(a0[i], a0[i], dp0);
                dp1 = fmaf(a1[i], a1[i], dp1);
                dp2 = fmaf(a2[i], a2[i], dp2);
                dp3 = fmaf(a3[i], a3[i], dp3);
            }
            dp[t] = (dp0 + dp1) + (dp2 + dp3);
        }

        // transpose-reduce: lane with quad-id q ends with the full quad sum
        // of tile q (same add tree as quad_sum: (^16 pair) + (^32 pair))
        float a01 = q0 ? dp[1] : dp[0];
        float g01 = q0 ? dp[0] : dp[1];
        float a23 = q0 ? dp[3] : dp[2];
        float g23 = q0 ? dp[2] : dp[3];
        float s01 = a01 + __shfl_xor(g01, 16, 64);
        float s23 = a23 + __shfl_xor(g23, 16, 64);
        float aa = q1 ? s23 : s01;
        float gg = q1 ? s01 : s23;
        float dpq = aa + __shfl_xor(gg, 32, 64);

        float d = fmaxf(dpq, 1e-30f);
        slog = fmaf(wcc, __builtin_amdgcn_logf(d), slog);
    }

    // lane (q,ln) holds slog for sample q*16+ln -> direct full-wave store
    out[base + lane] = __builtin_amdgcn_exp2f(slog);
}

extern "C" void kernel_launch(void* const* d_in, const int* in_sizes, int n_in,
                              void* d_out, int out_size, void* d_ws, size_t ws_size,
                              hipStream_t stream) {
    const float* X       = (const float*)d_in[0];
    const float* Ainv    = (const float*)d_in[1];
    const float* means   = (const float*)d_in[2];
    const float* weights = (const float*)d_in[3];
    float* out = (float*)d_out;
    const int N = in_sizes[0] / 64;

    short* AbP16 = (short*)d_ws;                       // 131072 B
    float* biasP = (float*)((char*)d_ws + 131072);     // 4096 B

    gmm_prep<<<dim3(16), dim3(256), 0, stream>>>(Ainv, means, AbP16, biasP);
    gmm_main<<<dim3(N / 256), dim3(256), 0, stream>>>(X, weights, AbP16, biasP, out);
}

// Round 12
// 136.591 us; speedup vs baseline: 2.9866x; 1.0145x over previous
//
#include <hip/hip_runtime.h>

typedef __attribute__((ext_vector_type(4))) float f32x4;
typedef __attribute__((ext_vector_type(8))) short bf16x8;

__device__ __forceinline__ short f2bf(float f) {
    union { float f; unsigned u; } v; v.f = f;
    unsigned u = v.u + 0x7FFFu + ((v.u >> 16) & 1u);   // RNE
    return (short)(u >> 16);
}
__device__ __forceinline__ int pack_bf2(float a, float b) {
    union { float f; unsigned u; } ua, ub; ua.f = a; ub.f = b;
    unsigned x = ua.u + 0x8000u, y = ub.u + 0x8000u;   // round half-up
    return (int)__builtin_amdgcn_perm(y, x, 0x07060302u);
}

// sum over lanes {l, l^16, l^32, l^48}.
// gfx950 permlane{16,32}_swap: VALU pipe, no DS traffic. Verified on-HW (r3).
#if __has_builtin(__builtin_amdgcn_permlane16_swap) && \
    __has_builtin(__builtin_amdgcn_permlane32_swap)
__device__ __forceinline__ float quad_sum(float dp) {
    unsigned u = __float_as_uint(dp);
    auto r1 = __builtin_amdgcn_permlane16_swap(u, u, false, false);
    float s = __uint_as_float(r1[0]) + __uint_as_float(r1[1]);
    unsigned v = __float_as_uint(s);
    auto r2 = __builtin_amdgcn_permlane32_swap(v, v, false, false);
    return __uint_as_float(r2[0]) + __uint_as_float(r2[1]);
}
#else
__device__ __forceinline__ float quad_sum(float dp) {
    dp += __shfl_xor(dp, 16, 64);
    dp += __shfl_xor(dp, 32, 64);
    return dp;
}
#endif

// ---------------------------------------------------------------------------
// Prep (16 blocks x 256): blocked Cholesky A = L·L^T (B=8), round-7 panel +
// REWRITTEN trailing update (was DS-throughput-bound: ~44 scalar b32 ops/row):
//  - panel also writes a compact TRANSPOSED copy sPt[k][j] (f32x4-aligned)
//  - trailing: 4x4 register tiles, LOWER tiles only (upper never read:
//    b/bias/pack/panel all guard k>=j), 24 x ds_read/write_b128 per tile
//  - kb loop fully unrolled -> nt compile-time, all indices static
// Stride 65 -> 68 (16 B alignment for b128; 68 == 4 mod 32 de-aliases banks).
// Then b = L^T m, biasP[c][p] = -b[pi(p)], fragment pack (frags 4,6 zero).
// ---------------------------------------------------------------------------
__global__ void gmm_prep(const float* __restrict__ Ainv,
                         const float* __restrict__ means,
                         short* __restrict__ AbP16,
                         float* __restrict__ biasP) {
    __shared__ float sA[64 * 68];      // 17.4 KB
    __shared__ float sPt[8 * 68];      // 2.2 KB transposed panel
    __shared__ float sm[64];
    __shared__ float sb[64];
    const int c = blockIdx.x, t = threadIdx.x;
    const float* A = Ainv + c * 4096;
    #pragma unroll
    for (int i = 0; i < 4; ++i) {      // vector stage, stride 68
        int flat = i * 1024 + t * 4;
        int r = flat >> 6, col = flat & 63;
        *(f32x4*)&sA[r * 68 + col] = *(const f32x4*)(A + flat);
    }
    if (t < 64) sm[t] = means[c * 64 + t];
    __syncthreads();

    #pragma unroll
    for (int kb = 0; kb < 8; ++kb) {
        const int k0 = kb * 8;
        if (t < 64) {                  // ---- panel: wave 0 (r7-proven) ----
            const int j = k0 + t;
            const bool act = (j < 64);
            const int jj = act ? j : 63;
            float pc[8];
            #pragma unroll
            for (int i = 0; i < 8; ++i) pc[i] = sA[jj * 68 + k0 + i];
            #pragma unroll
            for (int kk = 0; kk < 8; ++kk) {
                float diag = __shfl(pc[kk], kk, 64);
                float s = __builtin_sqrtf(diag);
                float inv = 1.f / s;
                if (t == kk)     pc[kk] = s;
                else if (t > kk) pc[kk] *= inv;
                #pragma unroll
                for (int i = kk + 1; i < 8; ++i) {
                    float lik = __shfl(pc[kk], i, 64);
                    if (t > kk) pc[i] = fmaf(-pc[kk], lik, pc[i]);
                }
            }
            if (act) {
                #pragma unroll
                for (int i = 0; i < 8; ++i) sA[j * 68 + k0 + i] = pc[i];
                #pragma unroll
                for (int i = 0; i < 8; ++i) sPt[i * 68 + j] = pc[i];
            }
        }
        __syncthreads();
        {   // ---- trailing rank-8 update: lower 4x4 tiles, b128 ----
            const int r0 = k0 + 8;
            const int W = 64 - r0;                 // compile-time (unrolled)
            if (W > 0) {
                const int nt = W >> 2;
                if (t < nt * nt) {
                    const int tj = t / nt;         // nt const -> magic mul
                    const int ti = t - tj * nt;
                    if (tj >= ti) {                // lower tiles only
                        const int j0 = r0 + tj * 4, i0 = r0 + ti * 4;
                        f32x4 a0 = {0.f,0.f,0.f,0.f}, a1 = a0, a2 = a0, a3 = a0;
                        #pragma unroll
                        for (int k = 0; k < 8; ++k) {
                            f32x4 pj = *(const f32x4*)&sPt[k * 68 + j0];
                            f32x4 pi = *(const f32x4*)&sPt[k * 68 + i0];
                            a0 += pi * pj[0]; a1 += pi * pj[1];
                            a2 += pi * pj[2]; a3 += pi * pj[3];
                        }
                        *(f32x4*)&sA[(j0 + 0) * 68 + i0] -= a0;
                        *(f32x4*)&sA[(j0 + 1) * 68 + i0] -= a1;
                        *(f32x4*)&sA[(j0 + 2) * 68 + i0] -= a2;
                        *(f32x4*)&sA[(j0 + 3) * 68 + i0] -= a3;
                    }
                }
            }
        }
        __syncthreads();
    }

    {   // b[j] = (L^T m)[j] = sum_{k>=j} L[k][j] m[k]
        int j = t >> 2, seg = t & 3;
        float p = 0.f;
        #pragma unroll
        for (int k2 = 0; k2 < 16; ++k2) {
            int k = seg * 16 + k2;
            float Mv = (k >= j) ? sA[k * 68 + j] : 0.f;
            p += Mv * sm[k];
        }
        p += __shfl_xor(p, 1, 64); p += __shfl_xor(p, 2, 64);
        if (seg == 0) sb[j] = p;
    }
    __syncthreads();
    if (t < 64) {
        int rt = t >> 4, qh = (t >> 2) & 3, r = t & 3;
        int pj = (rt >> 1) * 32 + 8 * qh + 4 * (rt & 1) + r;
        biasP[c * 64 + t] = -sb[pj];
    }
    #pragma unroll
    for (int rep = 0; rep < 2; ++rep) {     // permuted M = L^T fragments
        int f = rep * 256 + t;
        int rt = f >> 7, kc = (f >> 6) & 1, L = f & 63;
        int ln = L & 15, q = L >> 4;
        int pj = (rt >> 1) * 32 + 8 * (ln >> 2) + 4 * (rt & 1) + (ln & 3);
        int kbase = 32 * kc + 8 * q;
        bf16x8 v;
        #pragma unroll
        for (int j = 0; j < 8; ++j) {
            int kk = kbase + j;
            float x = (kk >= pj) ? sA[kk * 68 + pj] : 0.f;
            v[j] = f2bf(x);
        }
        *(bf16x8*)(AbP16 + c * 4096 + f * 8) = v;
    }
}

union BFrag { bf16x8 v; int i[4]; };

// ---------------------------------------------------------------------------
// Main (1024 blocks x 256) — byte-identical to round 7 (best measured main,
// 42-47 us): 4 waves x 64 samples; NO LDS, NO barriers; M-fragments straight
// from global (L2/L3-resident); M upper-triangular -> 6 MFMA + 6 af loads
// per comp; d = sum z^2; permlane quad reduction; coalesced store.
// ---------------------------------------------------------------------------
__global__ __launch_bounds__(256, 4) void gmm_main(
    const float* __restrict__ X,
    const float* __restrict__ weights,
    const short* __restrict__ AbP16,
    const float* __restrict__ biasP,
    float* __restrict__ out) {

    const int tid = threadIdx.x;
    const int lane = tid & 63, w = tid >> 6;
    const int q = lane >> 4, ln = lane & 15;
    const int base = blockIdx.x * 256 + w * 64;

    BFrag xb[4][2];
    #pragma unroll
    for (int t = 0; t < 4; ++t) {
        const float* xr = X + (size_t)(base + t * 16 + ln) * 64 + 8 * q;
        #pragma unroll
        for (int kc = 0; kc < 2; ++kc) {
            f32x4 a = *(const f32x4*)(xr + 32 * kc);
            f32x4 b = *(const f32x4*)(xr + 32 * kc + 4);
            xb[t][kc].i[0] = pack_bf2(a[0], a[1]);
            xb[t][kc].i[1] = pack_bf2(a[2], a[3]);
            xb[t][kc].i[2] = pack_bf2(b[0], b[1]);
            xb[t][kc].i[3] = pack_bf2(b[2], b[3]);
        }
    }

    float slog[4] = {0.f, 0.f, 0.f, 0.f};

    #pragma unroll 1
    for (int c = 0; c < 16; ++c) {
        const short* aP = AbP16 + c * 4096 + lane * 8;
        bf16x8 af0 = *(const bf16x8*)(aP + 0 * 512);   // rt0 kc0
        bf16x8 af1 = *(const bf16x8*)(aP + 1 * 512);   // rt0 kc1
        bf16x8 af2 = *(const bf16x8*)(aP + 2 * 512);   // rt1 kc0
        bf16x8 af3 = *(const bf16x8*)(aP + 3 * 512);   // rt1 kc1
        bf16x8 af5 = *(const bf16x8*)(aP + 5 * 512);   // rt2 kc1 (kc0 zero)
        bf16x8 af7 = *(const bf16x8*)(aP + 7 * 512);   // rt3 kc1 (kc0 zero)
        f32x4 bias[4];
        #pragma unroll
        for (int rt = 0; rt < 4; ++rt)
            bias[rt] = *(const f32x4*)(biasP + c * 64 + rt * 16 + q * 4);
        const float wcc = weights[c];

        #pragma unroll
        for (int t = 0; t < 4; ++t) {
            f32x4 a0 = __builtin_amdgcn_mfma_f32_16x16x32_bf16(af0, xb[t][0].v, bias[0], 0, 0, 0);
            a0 = __builtin_amdgcn_mfma_f32_16x16x32_bf16(af1, xb[t][1].v, a0, 0, 0, 0);
            f32x4 a1 = __builtin_amdgcn_mfma_f32_16x16x32_bf16(af2, xb[t][0].v, bias[1], 0, 0, 0);
            a1 = __builtin_amdgcn_mfma_f32_16x16x32_bf16(af3, xb[t][1].v, a1, 0, 0, 0);
            f32x4 a2 = __builtin_amdgcn_mfma_f32_16x16x32_bf16(af5, xb[t][1].v, bias[2], 0, 0, 0);
            f32x4 a3 = __builtin_amdgcn_mfma_f32_16x16x32_bf16(af7, xb[t][1].v, bias[3], 0, 0, 0);

            float dp0 = a0[0] * a0[0], dp1 = a1[0] * a1[0];
            float dp2 = a2[0] * a2[0], dp3 = a3[0] * a3[0];
            #pragma unroll
            for (int i = 1; i < 4; ++i) {
                dp0 = fmaf(a0[i], a0[i], dp0);
                dp1 = fmaf(a1[i], a1[i], dp1);
                dp2 = fmaf(a2[i], a2[i], dp2);
                dp3 = fmaf(a3[i], a3[i], dp3);
            }
            float dp = quad_sum((dp0 + dp1) + (dp2 + dp3));
            float d = fmaxf(dp, 1e-30f);
            slog[t] = fmaf(wcc, __builtin_amdgcn_logf(d), slog[t]);
        }
    }

    // slog[] identical across each quad after quad_sum: lane (q,ln)
    // writes sample q*16+ln -> one coalesced 64-wide store per wave
    float s0 = (q & 1) ? slog[1] : slog[0];
    float s1 = (q & 1) ? slog[3] : slog[2];
    float sv = (q & 2) ? s1 : s0;
    out[base + lane] = __builtin_amdgcn_exp2f(sv);
}

extern "C" void kernel_launch(void* const* d_in, const int* in_sizes, int n_in,
                              void* d_out, int out_size, void* d_ws, size_t ws_size,
                              hipStream_t stream) {
    const float* X       = (const float*)d_in[0];
    const float* Ainv    = (const float*)d_in[1];
    const float* means   = (const float*)d_in[2];
    const float* weights = (const float*)d_in[3];
    float* out = (float*)d_out;
    const int N = in_sizes[0] / 64;

    short* AbP16 = (short*)d_ws;                       // 131072 B
    float* biasP = (float*)((char*)d_ws + 131072);     // 4096 B

    gmm_prep<<<dim3(16), dim3(256), 0, stream>>>(Ainv, means, AbP16, biasP);
    gmm_main<<<dim3(N / 256), dim3(256), 0, stream>>>(X, weights, AbP16, biasP, out);
}